// Round 11
// baseline (512.347 us; speedup 1.0000x reference)
//
#include <hip/hip_runtime.h>

#define N_ENT 500000
#define E_NUM 400000

typedef __attribute__((ext_vector_type(8))) short short8;
typedef __attribute__((ext_vector_type(4))) short short4v;
typedef __attribute__((ext_vector_type(4))) float f32x4;

static __device__ __forceinline__ unsigned short f2bf(float f) {
    unsigned u = __float_as_uint(f);
    u += 0x7fffu + ((u >> 16) & 1u);
    return (unsigned short)(u >> 16);
}
static __device__ __forceinline__ float bf2f(unsigned short s) {
    return __uint_as_float(((unsigned)s) << 16);
}

// fp32 -> bf16 elementwise convert (W1_ent table, 128M elems), f32x4 in / 8B out
__global__ __launch_bounds__(256) void cvt_bf16_kernel(
    const float* __restrict__ src, unsigned short* __restrict__ dst, int n4) {
    int i = blockIdx.x * blockDim.x + threadIdx.x;
    int stride = gridDim.x * blockDim.x;
    for (; i < n4; i += stride) {
        f32x4 v = ((const f32x4*)src)[i];
        short4v o;
        o[0] = (short)f2bf(v[0]); o[1] = (short)f2bf(v[1]);
        o[2] = (short)f2bf(v[2]); o[3] = (short)f2bf(v[3]);
        ((short4v*)dst)[i] = o;
    }
}

// Pack B[K][N] (fp32) into bf16 MFMA-fragment-major layout for
// v_mfma_f32_16x16x32_bf16: frag f = kb*(N/16)+nb; lane l holds
// B[kb*32 + (l>>4)*8 + j][nb*16 + (l&15)], j=0..7 contiguous (16B/lane).
__global__ void pack_b_kernel(const float* __restrict__ src,
                              unsigned short* __restrict__ dst, int K, int N) {
    int p = blockIdx.x * blockDim.x + threadIdx.x;
    if (p >= K * N) return;
    int j = p & 7;
    int l = (p >> 3) & 63;
    int f = p >> 9;
    int nfr = N >> 4;
    int nb = f % nfr;
    int kb = f / nfr;
    int k = kb * 32 + ((l >> 4) << 3) + j;
    int n = nb * 16 + (l & 15);
    dst[p] = f2bf(src[(size_t)k * N + n]);
}

// Swizzled tile addressing (rows x 256 bf16, row stride 512B):
// byte ^= (row&7)<<4 kills the 512B-stride bank conflict on ds_read_b128.
// Swizzle only flips byte bits 4..6, so 16B chunks move as units.
__device__ __forceinline__ int lds_off(int row, int colb) {
    return ((row << 9) + colb) ^ ((row & 7) << 4);
}

// ===== r5-proven fused MLP, gathers from the bf16 table (512B rows).
// 64 edges/block, 256 thr = 4 waves. Phase 1: each wave owns 16 rows
// (burst-gather 512B/row as 2 dwordx4 over 16 lanes, land at swizzled
// LDS positions, RMW epilogue). Phases 2/3: wave owns a col slice.
__global__ __launch_bounds__(256, 4) void fused8(
    const int* __restrict__ ei, const float* __restrict__ attr,
    const unsigned short* __restrict__ tb, const float* __restrict__ b1,
    const float* __restrict__ b2, const float* __restrict__ b3,
    const unsigned short* __restrict__ w1rp,
    const unsigned short* __restrict__ w2p,
    const unsigned short* __restrict__ w3p,
    float* __restrict__ out)
{
    __shared__ char hb[64 * 512];  // 32 KB: G -> h -> h2, swizzled image

    const int tid = threadIdx.x;
    const int l = tid & 63;
    const int wv = tid >> 6;
    const int lr = l & 15;      // frag col (C) / frag row (A,B)
    const int lg = l >> 4;      // k-group / C row-group
    const int r0 = wv << 4;     // this wave's 16 rows (phase 1 / gather)
    const int myrow = l >> 4;   // gather: row-within-quad
    const int mycol = l & 15;   // gather: 32B chunk index

    const int bid = blockIdx.x;
    const int d = bid >= 6250 ? 1 : 0;
    const int e0 = (d ? bid - 6250 : bid) << 6;

    // --- ids (broadcast loads: 16 lanes share each address)
    int ids[4];
    #pragma unroll
    for (int q = 0; q < 4; ++q)
        ids[q] = ei[d * E_NUM + e0 + r0 + (q << 2) + myrow];

    // --- issue all 16 burst gathers (512B/row as 2 back-to-back dwordx4)
    short8 g[4][2];
    #pragma unroll
    for (int q = 0; q < 4; ++q) {
        const unsigned short* gp = tb + (size_t)ids[q] * 256 + (mycol << 4);
        g[q][0] = *(const short8*)(gp);
        g[q][1] = *(const short8*)(gp + 8);
    }

    // --- issue attr loads (overlap with gather flight)
    const float* ap = attr + (size_t)(e0 + r0 + lr) * 64 + (lg << 3);
    f32x4 ax[2][2];
    #pragma unroll
    for (int kb = 0; kb < 2; ++kb) {
        ax[kb][0] = *(const f32x4*)(ap + (kb << 5));
        ax[kb][1] = *(const f32x4*)(ap + (kb << 5) + 4);
    }

    // --- land gathers at SWIZZLED positions (16B units); g regs die here
    #pragma unroll
    for (int q = 0; q < 4; ++q) {
        int row = r0 + (q << 2) + myrow;
        *(short8*)(hb + lds_off(row, (mycol << 5))) = g[q][0];
        *(short8*)(hb + lds_off(row, (mycol << 5) + 16)) = g[q][1];
    }

    // --- phase 1 MFMA: rel_proj = attr @ W1r (acc[cf] covers all 256 cols)
    const f32x4 zero = {0.f, 0.f, 0.f, 0.f};
    f32x4 acc[16];
    #pragma unroll
    for (int i = 0; i < 16; ++i) acc[i] = zero;
    #pragma unroll
    for (int kb = 0; kb < 2; ++kb) {
        short8 af;
        #pragma unroll
        for (int j = 0; j < 4; ++j) {
            af[j] = (short)f2bf(ax[kb][0][j]);
            af[j + 4] = (short)f2bf(ax[kb][1][j]);
        }
        #pragma unroll
        for (int cf = 0; cf < 16; ++cf)
            acc[cf] = __builtin_amdgcn_mfma_f32_16x16x32_bf16(
                af, ((const short8*)w1rp)[(size_t)(kb * 16 + cf) * 64 + l],
                acc[cf], 0, 0, 0);
    }

    // --- epilogue: same-address RMW (wave-local rows; DS in-order per wave)
    #pragma unroll
    for (int reg = 0; reg < 4; ++reg) {
        int row = r0 + (lg << 2) + reg;
        #pragma unroll
        for (int cf = 0; cf < 16; ++cf) {
            int col = (cf << 4) + lr;
            int a = lds_off(row, col << 1);
            float v = acc[cf][reg] + bf2f(*(unsigned short*)(hb + a)) + b1[col];
            *(unsigned short*)(hb + a) = f2bf(fmaxf(v, 0.f));
        }
    }
    __syncthreads();

    // --- phase 2: h2 = relu(h @ W2 + b2); wave owns cols [wv*64, wv*64+64)
    f32x4 acc2[4][4];
    #pragma unroll
    for (int i = 0; i < 4; ++i)
        #pragma unroll
        for (int j = 0; j < 4; ++j) acc2[i][j] = zero;

    #pragma unroll 2
    for (int kb = 0; kb < 8; ++kb) {
        short8 a[4];
        #pragma unroll
        for (int mr = 0; mr < 4; ++mr)
            a[mr] = *(const short8*)(hb +
                lds_off(mr * 16 + lr, ((kb << 5) + (lg << 3)) << 1));
        #pragma unroll
        for (int mr = 0; mr < 4; ++mr)
            #pragma unroll
            for (int nf = 0; nf < 4; ++nf)
                acc2[mr][nf] = __builtin_amdgcn_mfma_f32_16x16x32_bf16(
                    a[mr],
                    ((const short8*)w2p)[(size_t)(kb * 16 + (wv << 2) + nf) * 64 + l],
                    acc2[mr][nf], 0, 0, 0);
    }
    __syncthreads();  // all phase-2 h reads done before overwrite

    #pragma unroll
    for (int mr = 0; mr < 4; ++mr)
        #pragma unroll
        for (int reg = 0; reg < 4; ++reg) {
            int row = mr * 16 + (lg << 2) + reg;
            #pragma unroll
            for (int nf = 0; nf < 4; ++nf) {
                int col = (wv << 6) + (nf << 4) + lr;
                float v = fmaxf(acc2[mr][nf][reg] + b2[col], 0.f);
                *(unsigned short*)(hb + lds_off(row, col << 1)) = f2bf(v);
            }
        }
    __syncthreads();

    // --- phase 3: out = h2 @ W3 + b3; wave owns cols [wv*32, wv*32+32)
    f32x4 acc3[4][2];
    #pragma unroll
    for (int i = 0; i < 4; ++i) { acc3[i][0] = zero; acc3[i][1] = zero; }

    #pragma unroll 2
    for (int kb = 0; kb < 8; ++kb) {
        short8 a[4];
        #pragma unroll
        for (int mr = 0; mr < 4; ++mr)
            a[mr] = *(const short8*)(hb +
                lds_off(mr * 16 + lr, ((kb << 5) + (lg << 3)) << 1));
        #pragma unroll
        for (int mr = 0; mr < 4; ++mr)
            #pragma unroll
            for (int nf = 0; nf < 2; ++nf)
                acc3[mr][nf] = __builtin_amdgcn_mfma_f32_16x16x32_bf16(
                    a[mr],
                    ((const short8*)w3p)[(size_t)(kb * 8 + (wv << 1) + nf) * 64 + l],
                    acc3[mr][nf], 0, 0, 0);
    }

    float* op = out + ((size_t)d * E_NUM + e0) * 128;
    #pragma unroll
    for (int mr = 0; mr < 4; ++mr)
        #pragma unroll
        for (int reg = 0; reg < 4; ++reg) {
            int row = mr * 16 + (lg << 2) + reg;
            #pragma unroll
            for (int nf = 0; nf < 2; ++nf) {
                int col = (wv << 5) + (nf << 4) + lr;
                op[(size_t)row * 128 + col] = acc3[mr][nf][reg] + b3[nf * 16 + (wv << 5) + lr];
            }
        }
}

extern "C" void kernel_launch(void* const* d_in, const int* in_sizes, int n_in,
                              void* d_out, int out_size, void* d_ws, size_t ws_size,
                              hipStream_t stream) {
    const int* ei     = (const int*)d_in[0];
    const float* attr = (const float*)d_in[1];
    const float* W1   = (const float*)d_in[2];
    const float* b1   = (const float*)d_in[3];
    const float* W2   = (const float*)d_in[4];
    const float* b2   = (const float*)d_in[5];
    const float* W3   = (const float*)d_in[6];
    const float* b3   = (const float*)d_in[7];
    float* out = (float*)d_out;
    const float* W1rel = W1 + (size_t)N_ENT * 256;

    // workspace layout: bf16 entity table (256 MB) + packed weights
    unsigned short* tb   = (unsigned short*)d_ws;            // 500000x256 bf16
    unsigned short* w1rp = tb + (size_t)N_ENT * 256;         //  64x256 bf16
    unsigned short* w2p  = w1rp + 64 * 256;                  // 256x256 bf16
    unsigned short* w3p  = w2p + 256 * 256;                  // 256x128 bf16

    // convert entity table fp32 -> bf16 (sequential, ~768 MB traffic)
    cvt_bf16_kernel<<<2048, 256, 0, stream>>>(W1, tb, N_ENT * 256 / 4);

    pack_b_kernel<<<(64 * 256) / 256, 256, 0, stream>>>(W1rel, w1rp, 64, 256);
    pack_b_kernel<<<(256 * 256) / 256, 256, 0, stream>>>(W2, w2p, 256, 256);
    pack_b_kernel<<<(256 * 128) / 256, 256, 0, stream>>>(W3, w3p, 256, 128);

    // 2 directions x 6250 tiles of 64 edges (exact, no tail)
    fused8<<<12500, 256, 0, stream>>>(ei, attr, tb, b1, b2, b3,
                                      w1rp, w2p, w3p, out);
}

// Round 12
// 426.035 us; speedup vs baseline: 1.2026x; 1.2026x over previous
//
#include <hip/hip_runtime.h>

#define N_ENT 500000
#define E_NUM 400000

typedef __attribute__((ext_vector_type(8))) short short8;
typedef __attribute__((ext_vector_type(4))) float f32x4;

static __device__ __forceinline__ unsigned short f2bf(float f) {
    unsigned u = __float_as_uint(f);
    u += 0x7fffu + ((u >> 16) & 1u);
    return (unsigned short)(u >> 16);
}
static __device__ __forceinline__ float bf2f(unsigned short s) {
    return __uint_as_float(((unsigned)s) << 16);
}

// Pack B[K][N] (fp32) into bf16 MFMA-fragment-major layout for
// v_mfma_f32_16x16x32_bf16: frag f = kb*(N/16)+nb; lane l holds
// B[kb*32 + (l>>4)*8 + j][nb*16 + (l&15)], j=0..7 contiguous (16B/lane).
__global__ void pack_b_kernel(const float* __restrict__ src,
                              unsigned short* __restrict__ dst, int K, int N) {
    int p = blockIdx.x * blockDim.x + threadIdx.x;
    if (p >= K * N) return;
    int j = p & 7;
    int l = (p >> 3) & 63;
    int f = p >> 9;
    int nfr = N >> 4;
    int nb = f % nfr;
    int kb = f / nfr;
    int k = kb * 32 + ((l >> 4) << 3) + j;
    int n = nb * 16 + (l & 15);
    dst[p] = f2bf(src[(size_t)k * N + n]);
}

// Swizzled tile addressing (rows x 256 bf16, row stride 512B):
// byte ^= (row&7)<<4 kills the 512B-stride bank conflict on ds_read_b128.
// Swizzle only flips byte bits 4..6, so 8B/16B chunks move as units.
__device__ __forceinline__ int lds_off(int row, int colb) {
    return ((row << 9) + colb) ^ ((row & 7) << 4);
}

// ===== Fully fused: out = relu(relu(gather + attr@W1r + b1)@W2 + b2)@W3 + b3
// 64 edges/block, 256 thr = 4 waves. Phase 1: each wave owns 16 rows,
// all 256 cols (burst-gather its rows, land at swizzled LDS positions,
// RMW epilogue). Phases 2/3: wave owns a 64-col slice, in-place h->h2.
__global__ __launch_bounds__(256, 4) void fused2(
    const int* __restrict__ ei, const float* __restrict__ attr,
    const float* __restrict__ W1, const float* __restrict__ b1,
    const float* __restrict__ b2, const float* __restrict__ b3,
    const unsigned short* __restrict__ w1rp,
    const unsigned short* __restrict__ w2p,
    const unsigned short* __restrict__ w3p,
    float* __restrict__ out)
{
    __shared__ char hb[64 * 512];  // 32 KB: G -> h -> h2, swizzled image

    const int tid = threadIdx.x;
    const int l = tid & 63;
    const int wv = tid >> 6;
    const int lr = l & 15;      // frag col (C) / frag row (A,B)
    const int lg = l >> 4;      // k-group / C row-group
    const int r0 = wv << 4;     // this wave's 16 rows (phase 1 / gather)
    const int myrow = l >> 4;   // gather: row-within-quad
    const int mycol = l & 15;   // gather: 16B chunk

    const int bid = blockIdx.x;
    const int d = bid >= 6250 ? 1 : 0;
    const int e0 = (d ? bid - 6250 : bid) << 6;

    // --- ids (broadcast loads: 16 lanes share each address)
    int ids[4];
    #pragma unroll
    for (int q = 0; q < 4; ++q)
        ids[q] = ei[d * E_NUM + e0 + r0 + (q << 2) + myrow];

    // --- issue all 16 burst gathers (1KB/row as 4 back-to-back dwordx4)
    f32x4 g[4][4];
    #pragma unroll
    for (int q = 0; q < 4; ++q) {
        const float* gp = W1 + (size_t)ids[q] * 256 + (mycol << 2);
        #pragma unroll
        for (int k = 0; k < 4; ++k)
            g[q][k] = *(const f32x4*)(gp + (k << 6));
    }

    // --- issue attr loads (overlap with gather flight)
    const float* ap = attr + (size_t)(e0 + r0 + lr) * 64 + (lg << 3);
    f32x4 ax[2][2];
    #pragma unroll
    for (int kb = 0; kb < 2; ++kb) {
        ax[kb][0] = *(const f32x4*)(ap + (kb << 5));
        ax[kb][1] = *(const f32x4*)(ap + (kb << 5) + 4);
    }

    // --- land gathers at SWIZZLED positions (bf16); g regs die here
    #pragma unroll
    for (int q = 0; q < 4; ++q) {
        int row = r0 + (q << 2) + myrow;
        #pragma unroll
        for (int k = 0; k < 4; ++k) {
            unsigned lo = ((unsigned)f2bf(g[q][k][1]) << 16) | f2bf(g[q][k][0]);
            unsigned hi = ((unsigned)f2bf(g[q][k][3]) << 16) | f2bf(g[q][k][2]);
            int a = lds_off(row, (k << 7) + (mycol << 3));
            *(unsigned*)(hb + a) = lo;
            *(unsigned*)(hb + a + 4) = hi;
        }
    }

    // --- phase 1 MFMA: rel_proj = attr @ W1r (acc[cf] covers all 256 cols)
    const f32x4 zero = {0.f, 0.f, 0.f, 0.f};
    f32x4 acc[16];
    #pragma unroll
    for (int i = 0; i < 16; ++i) acc[i] = zero;
    #pragma unroll
    for (int kb = 0; kb < 2; ++kb) {
        short8 af;
        #pragma unroll
        for (int j = 0; j < 4; ++j) {
            af[j] = (short)f2bf(ax[kb][0][j]);
            af[j + 4] = (short)f2bf(ax[kb][1][j]);
        }
        #pragma unroll
        for (int cf = 0; cf < 16; ++cf)
            acc[cf] = __builtin_amdgcn_mfma_f32_16x16x32_bf16(
                af, ((const short8*)w1rp)[(size_t)(kb * 16 + cf) * 64 + l],
                acc[cf], 0, 0, 0);
    }

    // --- epilogue: same-address RMW (wave-local rows; DS in-order per wave)
    #pragma unroll
    for (int reg = 0; reg < 4; ++reg) {
        int row = r0 + (lg << 2) + reg;
        #pragma unroll
        for (int cf = 0; cf < 16; ++cf) {
            int col = (cf << 4) + lr;
            int a = lds_off(row, col << 1);
            float v = acc[cf][reg] + bf2f(*(unsigned short*)(hb + a)) + b1[col];
            v = fmaxf(v, 0.f);
            *(unsigned short*)(hb + a) = f2bf(v);
        }
    }
    __syncthreads();

    // --- phase 2: h2 = relu(h @ W2 + b2); wave owns cols [wv*64, wv*64+64)
    f32x4 acc2[4][4];
    #pragma unroll
    for (int i = 0; i < 4; ++i)
        #pragma unroll
        for (int j = 0; j < 4; ++j) acc2[i][j] = zero;

    #pragma unroll 2
    for (int kb = 0; kb < 8; ++kb) {
        short8 a[4];
        #pragma unroll
        for (int mr = 0; mr < 4; ++mr)
            a[mr] = *(const short8*)(hb +
                lds_off(mr * 16 + lr, ((kb << 5) + (lg << 3)) << 1));
        #pragma unroll
        for (int mr = 0; mr < 4; ++mr)
            #pragma unroll
            for (int nf = 0; nf < 4; ++nf)
                acc2[mr][nf] = __builtin_amdgcn_mfma_f32_16x16x32_bf16(
                    a[mr],
                    ((const short8*)w2p)[(size_t)(kb * 16 + (wv << 2) + nf) * 64 + l],
                    acc2[mr][nf], 0, 0, 0);
    }
    __syncthreads();  // all phase-2 h reads done before overwrite

    #pragma unroll
    for (int mr = 0; mr < 4; ++mr)
        #pragma unroll
        for (int reg = 0; reg < 4; ++reg) {
            int row = mr * 16 + (lg << 2) + reg;
            #pragma unroll
            for (int nf = 0; nf < 4; ++nf) {
                int col = (wv << 6) + (nf << 4) + lr;
                float v = fmaxf(acc2[mr][nf][reg] + b2[col], 0.f);
                *(unsigned short*)(hb + lds_off(row, col << 1)) = f2bf(v);
            }
        }
    __syncthreads();

    // --- phase 3: out = h2 @ W3 + b3; wave owns cols [wv*32, wv*32+32)
    f32x4 acc3[4][2];
    #pragma unroll
    for (int i = 0; i < 4; ++i) { acc3[i][0] = zero; acc3[i][1] = zero; }

    #pragma unroll 2
    for (int kb = 0; kb < 8; ++kb) {
        short8 a[4];
        #pragma unroll
        for (int mr = 0; mr < 4; ++mr)
            a[mr] = *(const short8*)(hb +
                lds_off(mr * 16 + lr, ((kb << 5) + (lg << 3)) << 1));
        #pragma unroll
        for (int mr = 0; mr < 4; ++mr)
            #pragma unroll
            for (int nf = 0; nf < 2; ++nf)
                acc3[mr][nf] = __builtin_amdgcn_mfma_f32_16x16x32_bf16(
                    a[mr],
                    ((const short8*)w3p)[(size_t)(kb * 8 + (wv << 1) + nf) * 64 + l],
                    acc3[mr][nf], 0, 0, 0);
    }

    float* op = out + ((size_t)d * E_NUM + e0) * 128;
    #pragma unroll
    for (int mr = 0; mr < 4; ++mr)
        #pragma unroll
        for (int reg = 0; reg < 4; ++reg) {
            int row = mr * 16 + (lg << 2) + reg;
            #pragma unroll
            for (int nf = 0; nf < 2; ++nf) {
                int col = (wv << 5) + (nf << 4) + lr;
                op[(size_t)row * 128 + col] = acc3[mr][nf][reg] + b3[col];
            }
        }
}

extern "C" void kernel_launch(void* const* d_in, const int* in_sizes, int n_in,
                              void* d_out, int out_size, void* d_ws, size_t ws_size,
                              hipStream_t stream) {
    const int* ei     = (const int*)d_in[0];
    const float* attr = (const float*)d_in[1];
    const float* W1   = (const float*)d_in[2];
    const float* b1   = (const float*)d_in[3];
    const float* W2   = (const float*)d_in[4];
    const float* b2   = (const float*)d_in[5];
    const float* W3   = (const float*)d_in[6];
    const float* b3   = (const float*)d_in[7];
    float* out = (float*)d_out;
    const float* W1rel = W1 + (size_t)N_ENT * 256;

    unsigned short* w1rp = (unsigned short*)d_ws;   //  64x256 bf16 =  32 KB
    unsigned short* w2p  = w1rp + 64 * 256;         // 256x256 bf16 = 128 KB
    unsigned short* w3p  = w2p + 256 * 256;         // 256x128 bf16 =  64 KB

    pack_b_kernel<<<(64 * 256) / 256, 256, 0, stream>>>(W1rel, w1rp, 64, 256);
    pack_b_kernel<<<(256 * 256) / 256, 256, 0, stream>>>(W2, w2p, 256, 256);
    pack_b_kernel<<<(256 * 128) / 256, 256, 0, stream>>>(W3, w3p, 256, 128);

    // 2 directions x 6250 tiles of 64 edges (exact, no tail)
    fused2<<<12500, 256, 0, stream>>>(ei, attr, W1, b1, b2, b3,
                                      w1rp, w2p, w3p, out);
}